// Round 4
// baseline (10.440 us; speedup 1.0000x reference)
//
#include <hip/hip_runtime.h>
#include <hip/hip_bf16.h>

// Embedding via one-hot @ W.T  ==  gather of W columns.
// X: [B=2, S=2048] int32 indices in [0, 32000)
// W: [E=128, V=32000] float32 (nn.Linear weight layout)
// out[b,s,e] = W[e, X[b,s]]
//
// R1-R3 post-mortem: any direct column gather pays 16x line amplification
// (4B used per 64B line, stride-128KB reads) -> ~33.5MB random-line traffic
// from L3 at ~3.5TB/s -> 9.5us floor. L2 does NOT retain W across replays.
//
// R4: invert gather -> scatter. Each block owns 32 vocab columns, streams
// its 128e x 32v W tile with FULL line utilization (16.4MB total, L3-warm,
// streaming), transposes in LDS, scans X for matching tokens (mean 4.1 per
// block), writes their 512B embedding rows coalesced. No amplification.

#define VOCAB  32000
#define EMBED  128
#define NTOK   4096          // 2 * 2048
#define VCHUNK 32            // vocab columns per block
#define NBLK   (VOCAB / VCHUNK)   // 1000 blocks (= 8 * 125, XCD-balanced)
#define MAXM   96            // matched-token list capacity (mean 4.1, P(>96)~0)

__global__ __launch_bounds__(256) void embed_stream_scatter_kernel(
        const int* __restrict__ X,
        const float* __restrict__ W,
        float* __restrict__ out) {
    __shared__ float tile[VCHUNK][EMBED + 1];   // +1 pad: transpose writes <=2-way
    __shared__ int   mtok[MAXM];
    __shared__ int   mcnt;

    const int tid = threadIdx.x;
    const int v0  = blockIdx.x * VCHUNK;

    if (tid == 0) mcnt = 0;
    __syncthreads();

    // ---- Issue W tile loads early (hide latency under the X scan) ----
    // 128 e-rows x 8 float4 along v = 1024 float4; 4 per thread.
    // Lanes 0..7 share an e-row: 8 x 16B = 128B = 2 full aligned lines.
    float4 w[4];
    int e_[4], c_[4];
    #pragma unroll
    for (int k = 0; k < 4; ++k) {
        int fi = k * 256 + tid;
        int e  = fi >> 3;
        int c  = fi & 7;
        e_[k] = e; c_[k] = c;
        w[k] = *reinterpret_cast<const float4*>(
            &W[(size_t)e * VOCAB + v0 + c * 4]);
    }

    // ---- Scan X for tokens in [v0, v0+VCHUNK) ----
    const int4* X4 = reinterpret_cast<const int4*>(X);
    #pragma unroll
    for (int k = 0; k < 4; ++k) {
        int  i    = k * 256 + tid;     // int4 index 0..1023
        int4 xv   = X4[i];
        int  base = i * 4;
        int a0 = xv.x - v0, a1 = xv.y - v0, a2 = xv.z - v0, a3 = xv.w - v0;
        if ((unsigned)a0 < VCHUNK) { int s = atomicAdd(&mcnt, 1); if (s < MAXM) mtok[s] = ((base + 0) << 5) | a0; }
        if ((unsigned)a1 < VCHUNK) { int s = atomicAdd(&mcnt, 1); if (s < MAXM) mtok[s] = ((base + 1) << 5) | a1; }
        if ((unsigned)a2 < VCHUNK) { int s = atomicAdd(&mcnt, 1); if (s < MAXM) mtok[s] = ((base + 2) << 5) | a2; }
        if ((unsigned)a3 < VCHUNK) { int s = atomicAdd(&mcnt, 1); if (s < MAXM) mtok[s] = ((base + 3) << 5) | a3; }
    }

    // ---- Commit W tile to LDS, transposed: tile[v][e] ----
    // Write bank = (4c + j + e) % 32 over lanes (c,e): <=2-3-way, ~free (m136).
    #pragma unroll
    for (int k = 0; k < 4; ++k) {
        tile[c_[k] * 4 + 0][e_[k]] = w[k].x;
        tile[c_[k] * 4 + 1][e_[k]] = w[k].y;
        tile[c_[k] * 4 + 2][e_[k]] = w[k].z;
        tile[c_[k] * 4 + 3][e_[k]] = w[k].w;
    }
    __syncthreads();

    // ---- Scatter matched tokens: 32 lanes x float4 = 512B coalesced/token ----
    const int n    = min(mcnt, MAXM);
    const int g    = tid >> 5;
    const int lane = tid & 31;
    for (int m = g; m < n; m += 8) {
        int tok = mtok[m] >> 5;
        int v   = mtok[m] & (VCHUNK - 1);
        float4 o;
        o.x = tile[v][lane * 4 + 0];
        o.y = tile[v][lane * 4 + 1];
        o.z = tile[v][lane * 4 + 2];
        o.w = tile[v][lane * 4 + 3];
        *reinterpret_cast<float4*>(&out[(size_t)tok * EMBED + lane * 4]) = o;
    }
}

extern "C" void kernel_launch(void* const* d_in, const int* in_sizes, int n_in,
                              void* d_out, int out_size, void* d_ws, size_t ws_size,
                              hipStream_t stream) {
    const int*   X = (const int*)d_in[0];
    const float* W = (const float*)d_in[1];
    float*     out = (float*)d_out;

    embed_stream_scatter_kernel<<<NBLK, 256, 0, stream>>>(X, W, out);
}

// Round 5
// 9.551 us; speedup vs baseline: 1.0931x; 1.0931x over previous
//
#include <hip/hip_runtime.h>
#include <hip/hip_bf16.h>

// Embedding via one-hot @ W.T  ==  gather of W columns.
// X: [B=2, S=2048] int32 indices in [0, 32000)
// W: [E=128, V=32000] float32 (nn.Linear weight layout)
// out[b,s,e] = W[e, X[b,s]]
//
// R1-R4 post-mortem: R3 (2048 blks, 1 scalar/thread, XCD e-slicing) = 9.5us;
// R4 full-line streaming scatter REGRESSED (10.4us) -> traffic model alone
// is wrong. R1~R2 additivity paradox (adding a 33MB transpose kernel cost
// +0.3us) implies a large fixed per-replay constant (~8us) OR a dispatch
// ramp proportional to block count. R5 discriminates: 4x fewer blocks
// (512), ILP=4 per thread (4 independent gathers after one int4 X load),
// XCD e-slicing kept. Dispatch-ramp model predicts ~5us; fixed-overhead
// and service-ceiling models predict no change (~9.5us).

#define VOCAB  32000
#define EMBED  128
#define NTOK   4096          // 2 * 2048
#define NXCD   8
#define ESLICE (EMBED / NXCD)     // 16 e-values per XCD slice
#define TOKBLK 64                 // tokens per block
#define ILP    4                  // tokens per thread
#define NCHUNK (NTOK / TOKBLK)    // 64 token chunks
// grid = NCHUNK * NXCD = 512 blocks; 256 threads = 16 e x 16 token-groups

__global__ __launch_bounds__(256) void embed_gather_ilp_kernel(
        const int* __restrict__ X,
        const float* __restrict__ W,
        float* __restrict__ out) {
    // bid%8 -> XCD round-robin (m09): slice s pinned to XCD s; per-XCD W
    // footprint = 16 e-rows x 2000 v-lines ~ 1.78MB touched, fits 4MB L2.
    const int slice = blockIdx.x & (NXCD - 1);
    const int chunk = blockIdx.x >> 3;

    const int te = threadIdx.x & (ESLICE - 1);   // e within slice
    const int tg = threadIdx.x >> 4;             // token group 0..15

    const int e    = slice * ESLICE + te;
    const int tok0 = chunk * TOKBLK + tg * ILP;

    // One 16B X load per thread (16 lanes redundant -> L1 broadcast).
    const int4 idx4 = *reinterpret_cast<const int4*>(&X[tok0]);

    const float* Wrow = W + (size_t)e * VOCAB;

    // 4 independent scattered loads, all in flight together (vmcnt FIFO).
    const float v0 = Wrow[idx4.x];
    const float v1 = Wrow[idx4.y];
    const float v2 = Wrow[idx4.z];
    const float v3 = Wrow[idx4.w];

    // 16 lanes (same tg) write 64B contiguous per token.
    float* o = out + (size_t)tok0 * EMBED + e;
    o[0 * EMBED] = v0;
    o[1 * EMBED] = v1;
    o[2 * EMBED] = v2;
    o[3 * EMBED] = v3;
}

extern "C" void kernel_launch(void* const* d_in, const int* in_sizes, int n_in,
                              void* d_out, int out_size, void* d_ws, size_t ws_size,
                              hipStream_t stream) {
    const int*   X = (const int*)d_in[0];
    const float* W = (const float*)d_in[1];
    float*     out = (float*)d_out;

    embed_gather_ilp_kernel<<<NCHUNK * NXCD, 256, 0, stream>>>(X, W, out);
}